// Round 17
// baseline (84.593 us; speedup 1.0000x reference)
//
#include <hip/hip_runtime.h>
#include <math.h>

#define NN 8192
#define DIM 128
#define NBLK 2048   // (q 0..255) x (p 0..7)

typedef short bf16x8 __attribute__((ext_vector_type(8)));
typedef float f32x4 __attribute__((ext_vector_type(4)));

__device__ inline unsigned short f2bf(float x) {
    unsigned u = __float_as_uint(x);
    unsigned r = u + 0x7FFFu + ((u >> 16) & 1u);  // RNE
    return (unsigned short)(r >> 16);
}
__device__ inline float bf2f(unsigned short h) {
    return __uint_as_float(((unsigned)h) << 16);
}

// ---------------------------------------------------------------------------
// Kernel 0: pack mapping into MFMA-fragment-order bf16 chunks (1KB/wave-load).
// ---------------------------------------------------------------------------
__global__ void pack_kernel(const float* __restrict__ m, unsigned short* __restrict__ buf2) {
    const int t = threadIdx.x, l = t & 63;
    const int W = blockIdx.x * 4 + (t >> 6);
    const int g = W >> 2, kq = W & 3;
    const int row = g * 16 + (l & 15);
    const int k0 = kq * 32 + (l >> 4) * 8;
    const float* src = m + (size_t)row * DIM + k0;
    float4 v0 = *reinterpret_cast<const float4*>(src);
    float4 v1 = *reinterpret_cast<const float4*>(src + 4);
    float f[8] = {v0.x, v0.y, v0.z, v0.w, v1.x, v1.y, v1.z, v1.w};
    union { ushort4 u4[2]; unsigned short us[8]; } o;
#pragma unroll
    for (int q = 0; q < 8; ++q) o.us[q] = f2bf(f[q]);
    unsigned short* dst = buf2 + (size_t)W * 512 + l * 8;
    *reinterpret_cast<ushort4*>(dst) = o.u4[0];
    *reinterpret_cast<ushort4*>(dst + 4) = o.u4[1];
}

// ---------------------------------------------------------------------------
// Kernel 1: exact fp32 row norms
// ---------------------------------------------------------------------------
__global__ void sq_kernel(const float* __restrict__ mapping, float* __restrict__ sq) {
    int i = blockIdx.x * blockDim.x + threadIdx.x;
    if (i < NN) {
        const float4* row = reinterpret_cast<const float4*>(mapping + (size_t)i * DIM);
        float s = 0.f;
#pragma unroll
        for (int q = 0; q < DIM / 4; ++q) {
            float4 v = row[q];
            s += v.x * v.x + v.y * v.y + v.z * v.z + v.w * v.w;
        }
        sq[i] = s;
    }
}

// ---------------------------------------------------------------------------
// Kernel 2: P/C with 32x256 tiles and FULLY-CONTIGUOUS consumer D reads.
// Block (q,p): rows 32q..+31; tiles c = (q>>3)+p, +8, .. (<32).
// Producers (w 0-3): row-group rg=w&1, col-subtiles sh=(w>>1)*8..+7 ->
//   32 MFMA/tile/wave (r13's proven per-wave rate) -> bf16 d-tile in LDS
//   ring (4 slots, [32][264] pad -> 2-way write conflicts = free).
// Consumers (w 4-7): 8 rows each; ONE instruction = 64 lanes x 16B = 1KB
//   contiguous (entire row segment) — the fillBuffer access shape. 8
//   insts/tile/wave, named double buffer, only-D vmem FIFO.
// Barriers: r16's proven pattern (producer after odd tt/last; consumer
//   before even tt; slots disjoint mod 4).
// ---------------------------------------------------------------------------
__global__ __launch_bounds__(512, 4) void dist_kernel(const unsigned short* __restrict__ buf2,
                                                      const float* __restrict__ D,
                                                      const float* __restrict__ sq,
                                                      float* __restrict__ partials) {
    __shared__ __align__(16) unsigned short dts[4][32][264];  // 67.6KB ring
    __shared__ float wred[8];

    const int t = threadIdx.x, l = t & 63, w = t >> 6;
    const int b = blockIdx.x;
    const int q = b >> 3, p = b & 7;
    const int c0 = (q >> 3) + p;
    float psum = 0.f;

    if (c0 < 32) {
        const int nt = ((31 - c0) >> 3) + 1;
        const int l15 = l & 15, hi = l >> 4;

        if (w < 4) {
            // ========================= PRODUCER =========================
            const int rg = w & 1, sh = (w >> 1) * 8;
            const int i_row = q * 32 + rg * 16 + l15;
            bf16x8 af[4];
#pragma unroll
            for (int kq = 0; kq < 4; ++kq)
                af[kq] = *(const bf16x8*)(buf2 + (size_t)((q * 2 + rg) * 4 + kq) * 512 + l * 8);
            const float sa = sq[i_row];

            for (int tt = 0; tt < nt; ++tt) {
                const int c = c0 + tt * 8;
                unsigned short (*slot)[264] = dts[tt & 3];
#pragma unroll
                for (int s2 = 0; s2 < 8; ++s2) {
                    const int s = sh + s2;
                    bf16x8 bfr[4];
#pragma unroll
                    for (int kq = 0; kq < 4; ++kq)
                        bfr[kq] = *(const bf16x8*)(buf2 + (size_t)((c * 16 + s) * 4 + kq) * 512 + l * 8);
                    f32x4 sb = *(const f32x4*)(sq + c * 256 + s * 16 + hi * 4);
                    f32x4 acc = {};
#pragma unroll
                    for (int kq = 0; kq < 4; ++kq)
                        acc = __builtin_amdgcn_mfma_f32_16x16x32_bf16(bfr[kq], af[kq], acc, 0, 0, 0);
                    ushort4 o;
                    unsigned short* op = (unsigned short*)&o;
#pragma unroll
                    for (int r = 0; r < 4; ++r) {
                        float d2 = fmaf(-2.f, acc[r], sa + sb[r]);
                        op[r] = f2bf(sqrtf(fmaxf(d2, 0.f)));
                    }
                    *reinterpret_cast<ushort4*>(&slot[rg * 16 + l15][s * 16 + hi * 4]) = o;
                }
                if ((tt & 1) == 1 || tt == nt - 1) {
                    asm volatile("s_waitcnt lgkmcnt(0)" ::: "memory");
                    __builtin_amdgcn_sched_barrier(0);
                    __builtin_amdgcn_s_barrier();
                }
            }
        } else {
            // ========================= CONSUMER =========================
            const int cw = w - 4;
            const int row0 = cw * 8;               // first of this wave's 8 rows
            const size_t Dbase = (size_t)(q * 32 + row0) * NN + l * 4;
            const int cdiag = q >> 3;

            f32x4 dA[8], dB[8];

            auto consume = [&](int tt, const f32x4(&dd)[8]) {
                const int c = c0 + tt * 8;
                const unsigned short (*slot)[264] = dts[tt & 3];
                if (c != cdiag) {
#pragma unroll
                    for (int k = 0; k < 8; ++k) {
                        ushort4 dv = *reinterpret_cast<const ushort4*>(&slot[row0 + k][l * 4]);
                        const unsigned short* dp = (const unsigned short*)&dv;
#pragma unroll
                        for (int r = 0; r < 4; ++r) {
                            float Dv = dd[k][r];
                            psum += __fdividef(fabsf(bf2f(dp[r]) - Dv), Dv);
                        }
                    }
                } else {
#pragma unroll
                    for (int k = 0; k < 8; ++k) {
                        const int i_g = q * 32 + row0 + k;
                        ushort4 dv = *reinterpret_cast<const ushort4*>(&slot[row0 + k][l * 4]);
                        const unsigned short* dp = (const unsigned short*)&dv;
#pragma unroll
                        for (int r = 0; r < 4; ++r) {
                            const int j = c * 256 + l * 4 + r;
                            if (j > i_g) {
                                float Dv = dd[k][r];
                                psum += __fdividef(fabsf(bf2f(dp[r]) - Dv), Dv);
                            }
                        }
                    }
                }
            };

            // prefetch tile 0 (1KB-contiguous per instruction)
#pragma unroll
            for (int k = 0; k < 8; ++k)
                dA[k] = *(const f32x4*)(D + Dbase + (size_t)k * NN + c0 * 256);

            bool cur_a = true;
            for (int tt = 0; tt < nt; ++tt) {
                if ((tt & 1) == 0) __builtin_amdgcn_s_barrier();
                const int cn = c0 + (tt + 1) * 8;
                if (cur_a) {
                    if (tt + 1 < nt) {
#pragma unroll
                        for (int k = 0; k < 8; ++k)
                            dB[k] = *(const f32x4*)(D + Dbase + (size_t)k * NN + cn * 256);
                    }
                    consume(tt, dA);
                } else {
                    if (tt + 1 < nt) {
#pragma unroll
                        for (int k = 0; k < 8; ++k)
                            dA[k] = *(const f32x4*)(D + Dbase + (size_t)k * NN + cn * 256);
                    }
                    consume(tt, dB);
                }
                cur_a = !cur_a;
            }
        }
    }

    // ---- deterministic block reduction (producers contribute 0) ----
    for (int off = 32; off > 0; off >>= 1) psum += __shfl_down(psum, off, 64);
    __syncthreads();
    if (l == 0) wred[w] = psum;
    __syncthreads();
    if (t == 0) {
        float s = 0.f;
#pragma unroll
        for (int k = 0; k < 8; ++k) s += wred[k];
        partials[b] = 2.f * s;
    }
}

// ---------------------------------------------------------------------------
// Kernel 3: deterministic final reduction
// ---------------------------------------------------------------------------
__global__ void reduce_kernel(const float* __restrict__ partials, float* __restrict__ out) {
    __shared__ double sm[256];
    const int t = threadIdx.x;
    double s = 0.0;
    for (int i = t; i < NBLK; i += 256) s += (double)partials[i];
    sm[t] = s;
    __syncthreads();
    for (int off = 128; off > 0; off >>= 1) {
        if (t < off) sm[t] += sm[t + off];
        __syncthreads();
    }
    if (t == 0) out[0] = (float)(sm[0] / ((double)NN * (double)NN - (double)NN));
}

// ---------------------------------------------------------------------------
extern "C" void kernel_launch(void* const* d_in, const int* in_sizes, int n_in,
                              void* d_out, int out_size, void* d_ws, size_t ws_size,
                              hipStream_t stream) {
    const float* mapping = (const float*)d_in[0];
    const float* D       = (const float*)d_in[1];
    float* out = (float*)d_out;

    unsigned short* buf2 = (unsigned short*)d_ws;        // NN*DIM bf16 = 2 MiB
    float* sq            = (float*)(buf2 + NN * DIM);    // NN floats
    float* partials      = sq + NN;                      // NBLK floats

    pack_kernel<<<512, 256, 0, stream>>>(mapping, buf2);
    sq_kernel<<<NN / 256, 256, 0, stream>>>(mapping, sq);
    dist_kernel<<<NBLK, 512, 0, stream>>>(buf2, D, sq, partials);
    reduce_kernel<<<1, 256, 0, stream>>>(partials, out);
}